// Round 1
// 486.391 us; speedup vs baseline: 1.1094x; 1.1094x over previous
//
#include <hip/hip_runtime.h>
#include <math.h>

constexpr int B_ = 2, S_ = 1024, DM_ = 1024, NH_ = 16, HD_ = 64;
constexpr long SD = (long)S_ * DM_;   // per-batch hidden stride (1M)
constexpr long SS = (long)S_ * S_;    // per-head attn stride (1M)

typedef _Float16 half8 __attribute__((ext_vector_type(8)));
typedef _Float16 half4 __attribute__((ext_vector_type(4)));
typedef float floatx4 __attribute__((ext_vector_type(4)));

// async global->LDS, 16 B per lane; LDS dst is wave-uniform base + lane*16
__device__ __forceinline__ void gl_lds16(const void* g, void* l) {
    __builtin_amdgcn_global_load_lds(
        (const __attribute__((address_space(1))) void*)g,
        (__attribute__((address_space(3))) void*)l, 16, 0, 0);
}

// ---------------------------------------------------------------------------
// fp32 -> fp16 convert (4 elems/thread)
// ---------------------------------------------------------------------------
__global__ __launch_bounds__(256) void cvt_f2h(
    const float* __restrict__ x, _Float16* __restrict__ y, int n4)
{
    int i = (blockIdx.x * 256 + threadIdx.x);
    if (i < n4) {
        float4 v = ((const float4*)x)[i];
        half4 h = { (_Float16)v.x, (_Float16)v.y, (_Float16)v.z, (_Float16)v.w };
        ((half4*)y)[i] = h;
    }
}

// ---------------------------------------------------------------------------
// Unified NT MFMA GEMM: C = scale*(A @ W^T) [+bias] [*rowscale[row]].
// A: (M x K) k-contiguous (fp16, or fp32 when CONVA=1 -> converted in staging).
// W: (N x K) k-contiguous fp16. Batched over z=(b*NH+h) via element strides.
// mode 0: fp32 out (Cf).  mode 1: fp16 out (Ch).
// Block 256 = 4 waves in 2x2; wave computes WM x WN via 16x16x32 f16 MFMA.
// ---------------------------------------------------------------------------
template <int BM, int BN, int WM, int WN, int CONVA>
__global__ __launch_bounds__(256) void mm_nt(
    const void* __restrict__ Ap, const _Float16* __restrict__ Wp,
    const float* __restrict__ bias, const float* __restrict__ rowscale,
    float* __restrict__ Cf,
    _Float16* __restrict__ Ch, int K, int lda, int ldw, int ldc,
    long sAb, long sAh, long sWb, long sWh, long sCb, long sCh,
    float scale, int mode)
{
    constexpr int MI = WM / 16, NI = WN / 16;
    const int z = blockIdx.z, b = z / NH_, h = z % NH_;
    const int wave = threadIdx.x >> 6, lane = threadIdx.x & 63;
    const int m0 = blockIdx.y * BM, n0 = blockIdx.x * BN;
    const int wm = (wave >> 1) * WM, wn = (wave & 1) * WN;
    const int r16 = lane & 15, quad = lane >> 4;

    const _Float16* Wz = Wp + (long)b * sWb + (long)h * sWh;

    __shared__ __align__(16) _Float16 As[BM * 32];
    __shared__ __align__(16) _Float16 Bs[BN * 32];

    floatx4 acc[MI][NI];
#pragma unroll
    for (int i = 0; i < MI; ++i)
#pragma unroll
        for (int j = 0; j < NI; ++j)
#pragma unroll
            for (int r = 0; r < 4; ++r) acc[i][j][r] = 0.f;

    for (int k0 = 0; k0 < K; k0 += 32) {
        if constexpr (CONVA) {
            const float* Af = (const float*)Ap + (long)b * sAb + (long)h * sAh;
#pragma unroll
            for (int r = 0; r < BM / 32; ++r) {
                int idx = r * 1024 + threadIdx.x * 4;
                int row = idx >> 5, col = idx & 31;
                float4 v = *(const float4*)(Af + (long)(m0 + row) * lda + k0 + col);
                half4 hv = { (_Float16)v.x, (_Float16)v.y, (_Float16)v.z, (_Float16)v.w };
                *(half4*)&As[row * 32 + col] = hv;
            }
        } else {
            const _Float16* Ah = (const _Float16*)Ap + (long)b * sAb + (long)h * sAh;
#pragma unroll
            for (int c = wave * (BM / 64); c < (wave + 1) * (BM / 64); ++c) {
                const _Float16* g = Ah + (long)(m0 + c * 16 + (lane >> 2)) * lda
                                    + k0 + (lane & 3) * 8;
                gl_lds16(g, &As[c * 512]);
            }
        }
#pragma unroll
        for (int c = wave * (BN / 64); c < (wave + 1) * (BN / 64); ++c) {
            const _Float16* g = Wz + (long)(n0 + c * 16 + (lane >> 2)) * ldw
                                + k0 + (lane & 3) * 8;
            gl_lds16(g, &Bs[c * 512]);
        }
        __syncthreads();

        half8 af[MI], bf8[NI];
#pragma unroll
        for (int i = 0; i < MI; ++i)
            af[i] = *(const half8*)&As[(wm + i * 16 + r16) * 32 + quad * 8];
#pragma unroll
        for (int j = 0; j < NI; ++j)
            bf8[j] = *(const half8*)&Bs[(wn + j * 16 + r16) * 32 + quad * 8];
#pragma unroll
        for (int i = 0; i < MI; ++i)
#pragma unroll
            for (int j = 0; j < NI; ++j)
                acc[i][j] = __builtin_amdgcn_mfma_f32_16x16x32_f16(
                    af[i], bf8[j], acc[i][j], 0, 0, 0);
        __syncthreads();
    }

    const long cb = (long)b * sCb + (long)h * sCh;
#pragma unroll
    for (int i = 0; i < MI; ++i) {
#pragma unroll
        for (int j = 0; j < NI; ++j) {
#pragma unroll
            for (int r = 0; r < 4; ++r) {
                int row = m0 + wm + i * 16 + quad * 4 + r;
                int col = n0 + wn + j * 16 + r16;
                float v = acc[i][j][r] * scale;
                if (bias) v += bias[col];
                if (rowscale) v *= rowscale[(long)z * 1024 + row];
                if (mode == 0) Cf[cb + (long)row * ldc + col] = v;
                else           Ch[cb + (long)row * ldc + col] = (_Float16)v;
            }
        }
    }
}

// ---------------------------------------------------------------------------
// Fused QKV projection: z = blockIdx.z selects {Q,K,V}. M=2048, N=1024, K=1024.
// Q,K written fp16 row-major; V written fp16 TRANSPOSED per head:
// VtH[((b*16+h)*64+d)*1024 + s].
// ---------------------------------------------------------------------------
__global__ __launch_bounds__(256) void qkv_proj(
    const _Float16* __restrict__ hsH,
    const _Float16* __restrict__ W0, const _Float16* __restrict__ W1,
    const _Float16* __restrict__ W2,
    const float* __restrict__ b0, const float* __restrict__ b1,
    const float* __restrict__ b2,
    _Float16* __restrict__ QH, _Float16* __restrict__ KH,
    _Float16* __restrict__ VtH)
{
    const int z = blockIdx.z;
    const _Float16* W = (z == 0) ? W0 : (z == 1) ? W1 : W2;
    const float* bias = (z == 0) ? b0 : (z == 1) ? b1 : b2;

    const int wave = threadIdx.x >> 6, lane = threadIdx.x & 63;
    const int m0 = blockIdx.y * 128, n0 = blockIdx.x * 128;
    const int wm = (wave >> 1) * 64, wn = (wave & 1) * 64;
    const int r16 = lane & 15, quad = lane >> 4;

    __shared__ __align__(16) _Float16 As[128 * 32];
    __shared__ __align__(16) _Float16 Bs[128 * 32];

    floatx4 acc[4][4];
#pragma unroll
    for (int i = 0; i < 4; ++i)
#pragma unroll
        for (int j = 0; j < 4; ++j)
#pragma unroll
            for (int r = 0; r < 4; ++r) acc[i][j][r] = 0.f;

    for (int k0 = 0; k0 < 1024; k0 += 32) {
#pragma unroll
        for (int c = wave * 2; c < wave * 2 + 2; ++c) {
            const _Float16* ga = hsH + (long)(m0 + c * 16 + (lane >> 2)) * 1024
                                 + k0 + (lane & 3) * 8;
            gl_lds16(ga, &As[c * 512]);
            const _Float16* gb = W + (long)(n0 + c * 16 + (lane >> 2)) * 1024
                                 + k0 + (lane & 3) * 8;
            gl_lds16(gb, &Bs[c * 512]);
        }
        __syncthreads();

        half8 af[4], bf8[4];
#pragma unroll
        for (int i = 0; i < 4; ++i)
            af[i] = *(const half8*)&As[(wm + i * 16 + r16) * 32 + quad * 8];
#pragma unroll
        for (int j = 0; j < 4; ++j)
            bf8[j] = *(const half8*)&Bs[(wn + j * 16 + r16) * 32 + quad * 8];
#pragma unroll
        for (int i = 0; i < 4; ++i)
#pragma unroll
            for (int j = 0; j < 4; ++j)
                acc[i][j] = __builtin_amdgcn_mfma_f32_16x16x32_f16(
                    af[i], bf8[j], acc[i][j], 0, 0, 0);
        __syncthreads();
    }

    _Float16* dst = (z == 0) ? QH : KH;
#pragma unroll
    for (int i = 0; i < 4; ++i) {
#pragma unroll
        for (int j = 0; j < 4; ++j) {
#pragma unroll
            for (int r = 0; r < 4; ++r) {
                int row = m0 + wm + i * 16 + quad * 4 + r;
                int col = n0 + wn + j * 16 + r16;
                float v = acc[i][j][r] + bias[col];
                if (z < 2) {
                    dst[(long)row * 1024 + col] = (_Float16)v;
                } else {
                    int bb = row >> 10, s = row & 1023;
                    int hh = col >> 6, d = col & 63;
                    VtH[((((long)bb * 16 + hh) * 64 + d) << 10) | s] = (_Float16)v;
                }
            }
        }
    }
}

// ---------------------------------------------------------------------------
// Fused attention block: per (b,h) and 32-row Q block:
//   scores = Q Kh^T (MFMA, fragments straight from global/L2, K=64)
//   softmax in-register (wave shfl_xor + cross-wave LDS reduce)
//   write normalized probs once to trueA (fp32) and keep fp16 P in LDS
//   ctx = P @ V (A from swizzled LDS, B from VtH), write ctxH (B,S,DM) fp16
// Block = 512 thr (8 waves). Scores: wave w owns cols w*128..w*128+128.
// PV: wave -> d-slice (w&3)*16, k-half (w>>2); k-reduce via LDS.
// LDS: single 64 KB buffer, phase-aliased (red arrays / P / k-reduce scratch).
// ---------------------------------------------------------------------------
__global__ __launch_bounds__(512) void attn_fused(
    const _Float16* __restrict__ Q, const _Float16* __restrict__ K,
    const _Float16* __restrict__ Vt, float* __restrict__ trueA,
    _Float16* __restrict__ ctx)
{
    const int z = blockIdx.y, b = z >> 4, h = z & 15;
    const int m0 = blockIdx.x * 32;
    const int wave = threadIdx.x >> 6, lane = threadIdx.x & 63;
    const int r16 = lane & 15, quad = lane >> 4;
    const int c0 = wave * 128;

    __shared__ __align__(16) _Float16 Ps[32 * 1024];   // 64 KB, phase-aliased
    float* redmx = (float*)Ps;          // [8][32]
    float* redsm = (float*)Ps + 256;    // [8][32]
    float* kred  = (float*)Ps;          // [4][2][64][4]

    const _Float16* Qb = Q + (long)b * SD + h * 64;
    const _Float16* Kb = K + (long)b * SD + h * 64;

    // ---- scores: rows m0..m0+31, cols c0..c0+127, K=64
    half8 af[2][2];
#pragma unroll
    for (int mi = 0; mi < 2; ++mi)
#pragma unroll
        for (int ks = 0; ks < 2; ++ks)
            af[mi][ks] = *(const half8*)&Qb[(long)(m0 + mi * 16 + r16) * DM_
                                            + ks * 32 + quad * 8];

    floatx4 acc[2][8];
#pragma unroll
    for (int mi = 0; mi < 2; ++mi)
#pragma unroll
        for (int nj = 0; nj < 8; ++nj)
#pragma unroll
            for (int r = 0; r < 4; ++r) acc[mi][nj][r] = 0.f;

#pragma unroll
    for (int ks = 0; ks < 2; ++ks) {
#pragma unroll
        for (int nj = 0; nj < 8; ++nj) {
            half8 bf = *(const half8*)&Kb[(long)(c0 + nj * 16 + r16) * DM_
                                          + ks * 32 + quad * 8];
            acc[0][nj] = __builtin_amdgcn_mfma_f32_16x16x32_f16(
                af[0][ks], bf, acc[0][nj], 0, 0, 0);
            acc[1][nj] = __builtin_amdgcn_mfma_f32_16x16x32_f16(
                af[1][ks], bf, acc[1][nj], 0, 0, 0);
        }
    }

    // ---- row max over all 1024 cols
    float rmx[2][4];
#pragma unroll
    for (int mi = 0; mi < 2; ++mi)
#pragma unroll
        for (int r = 0; r < 4; ++r) {
            float m = acc[mi][0][r];
#pragma unroll
            for (int nj = 1; nj < 8; ++nj) m = fmaxf(m, acc[mi][nj][r]);
#pragma unroll
            for (int o = 1; o <= 8; o <<= 1) m = fmaxf(m, __shfl_xor(m, o, 64));
            rmx[mi][r] = m;
        }
    if (r16 == 0) {
#pragma unroll
        for (int mi = 0; mi < 2; ++mi)
#pragma unroll
            for (int r = 0; r < 4; ++r)
                redmx[wave * 32 + mi * 16 + quad * 4 + r] = rmx[mi][r];
    }
    __syncthreads();
    float mx[2][4];
#pragma unroll
    for (int mi = 0; mi < 2; ++mi)
#pragma unroll
        for (int r = 0; r < 4; ++r) {
            float m = redmx[mi * 16 + quad * 4 + r];
#pragma unroll
            for (int w = 1; w < 8; ++w)
                m = fmaxf(m, redmx[w * 32 + mi * 16 + quad * 4 + r]);
            mx[mi][r] = m;
        }

    // ---- p = exp((s - max) * 1/8), row sum
    float rsm[2][4];
#pragma unroll
    for (int mi = 0; mi < 2; ++mi)
#pragma unroll
        for (int r = 0; r < 4; ++r) {
            float s = 0.f;
#pragma unroll
            for (int nj = 0; nj < 8; ++nj) {
                float p = __expf((acc[mi][nj][r] - mx[mi][r]) * 0.125f);
                acc[mi][nj][r] = p;
                s += p;
            }
#pragma unroll
            for (int o = 1; o <= 8; o <<= 1) s += __shfl_xor(s, o, 64);
            rsm[mi][r] = s;
        }
    if (r16 == 0) {
#pragma unroll
        for (int mi = 0; mi < 2; ++mi)
#pragma unroll
            for (int r = 0; r < 4; ++r)
                redsm[wave * 32 + mi * 16 + quad * 4 + r] = rsm[mi][r];
    }
    __syncthreads();
    float inv[2][4];
#pragma unroll
    for (int mi = 0; mi < 2; ++mi)
#pragma unroll
        for (int r = 0; r < 4; ++r) {
            float s = 0.f;
#pragma unroll
            for (int w = 0; w < 8; ++w)
                s += redsm[w * 32 + mi * 16 + quad * 4 + r];
            inv[mi][r] = 1.f / s;
        }
    __syncthreads();   // red reads done; Ps region can be overwritten

    // ---- write normalized probs: trueA (fp32) + Ps (fp16, XOR-swizzled: G4)
    float* Ta = trueA + (long)z * SS + (long)m0 * S_;
#pragma unroll
    for (int mi = 0; mi < 2; ++mi) {
#pragma unroll
        for (int r = 0; r < 4; ++r) {
            const int row = mi * 16 + quad * 4 + r;
            const int sw = (row & 7) << 3;
            const float iv = inv[mi][r];
#pragma unroll
            for (int nj = 0; nj < 8; ++nj) {
                const int col = c0 + nj * 16 + r16;
                const float v = acc[mi][nj][r] * iv;
                Ta[(long)row * S_ + col] = v;
                Ps[row * 1024 + (col ^ sw)] = (_Float16)v;
            }
        }
    }
    __syncthreads();   // Ps complete

    // ---- ctx = P @ V
    const int d0 = (wave & 3) * 16, kr = wave >> 2;
    const _Float16* Vb = Vt + ((long)z * 64 + d0 + r16) * (long)S_;
    floatx4 c2[2];
#pragma unroll
    for (int mi = 0; mi < 2; ++mi)
#pragma unroll
        for (int r = 0; r < 4; ++r) c2[mi][r] = 0.f;

    const int swz = (r16 & 7) << 3;     // same for rows r16 and 16+r16
#pragma unroll 4
    for (int k0 = kr * 512; k0 < kr * 512 + 512; k0 += 32) {
        half8 pa0 = *(const half8*)&Ps[r16 * 1024 + ((k0 + quad * 8) ^ swz)];
        half8 pa1 = *(const half8*)&Ps[(16 + r16) * 1024 + ((k0 + quad * 8) ^ swz)];
        half8 vf  = *(const half8*)&Vb[k0 + quad * 8];
        c2[0] = __builtin_amdgcn_mfma_f32_16x16x32_f16(pa0, vf, c2[0], 0, 0, 0);
        c2[1] = __builtin_amdgcn_mfma_f32_16x16x32_f16(pa1, vf, c2[1], 0, 0, 0);
    }

    __syncthreads();   // all Ps reads done; reuse LDS for k-reduce
    if (kr == 1) {
#pragma unroll
        for (int mi = 0; mi < 2; ++mi)
            *(floatx4*)&kred[(((wave & 3) * 2 + mi) * 64 + lane) * 4] = c2[mi];
    }
    __syncthreads();
    if (kr == 0) {
        _Float16* Cb = ctx + (long)b * SD + h * 64;
#pragma unroll
        for (int mi = 0; mi < 2; ++mi) {
            c2[mi] += *(const floatx4*)&kred[((wave * 2 + mi) * 64 + lane) * 4];
#pragma unroll
            for (int r = 0; r < 4; ++r) {
                const int srow = m0 + mi * 16 + quad * 4 + r;
                Cb[(long)srow * DM_ + d0 + r16] = (_Float16)c2[mi][r];
            }
        }
    }
}

// ---------------------------------------------------------------------------
// Hedgehog feature map: per (b,h): Y = Xh @ Wf^T + bf (K=64), out = fp16
// [exp(Y) | exp(-Y)] into (B,H,S,128).
// ---------------------------------------------------------------------------
__global__ __launch_bounds__(256) void feat_map(
    const _Float16* __restrict__ Xh, const _Float16* __restrict__ Wf,
    const float* __restrict__ bf, _Float16* __restrict__ outH)
{
    const int z = blockIdx.y, b = z >> 4, h = z & 15;
    const int m0 = blockIdx.x * 64;
    __shared__ float Xs[64][65];
    __shared__ float Ws[64][65];
    const _Float16* Xb = Xh + (long)b * SD + h * 64;
    for (int i = threadIdx.x; i < 4096; i += 256) {
        int r = i >> 6, c = i & 63;
        Xs[r][c] = (float)Xb[(long)(m0 + r) * 1024 + c];
        Ws[r][c] = (float)Wf[i];
    }
    __syncthreads();
    const int tm = (threadIdx.x >> 4) * 4, tn = (threadIdx.x & 15) * 4;
    float acc[4][4] = {{0.f}};
    for (int k = 0; k < 64; ++k) {
        float xv[4], wv[4];
#pragma unroll
        for (int i = 0; i < 4; ++i) xv[i] = Xs[tm + i][k];
#pragma unroll
        for (int j = 0; j < 4; ++j) wv[j] = Ws[tn + j][k];
#pragma unroll
        for (int i = 0; i < 4; ++i)
#pragma unroll
            for (int j = 0; j < 4; ++j) acc[i][j] = fmaf(xv[i], wv[j], acc[i][j]);
    }
#pragma unroll
    for (int i = 0; i < 4; ++i) {
        long base = ((long)z * S_ + m0 + tm + i) * 128;
#pragma unroll
        for (int j = 0; j < 4; ++j) {
            float y = acc[i][j] + bf[tn + j];
            outH[base + tn + j]      = (_Float16)expf(y);
            outH[base + 64 + tn + j] = (_Float16)expf(-y);
        }
    }
}

// ---------------------------------------------------------------------------
// sk[z][128] = sum_s fk[z][s][:]  (one block per z)
// ---------------------------------------------------------------------------
__global__ __launch_bounds__(256) void sum_fk(
    const _Float16* __restrict__ fkH, float* __restrict__ sk)
{
    const int z = blockIdx.x;
    const int col = threadIdx.x & 127, hlf = threadIdx.x >> 7;
    const _Float16* p = fkH + (long)z * S_ * 128 + (long)hlf * 512 * 128 + col;
    float s = 0.f;
    for (int i = 0; i < 512; ++i) s += (float)p[(long)i * 128];
    __shared__ float part[2][128];
    part[hlf][col] = s;
    __syncthreads();
    if (threadIdx.x < 128)
        sk[z * 128 + threadIdx.x] = part[0][threadIdx.x] + part[1][threadIdx.x];
}

// ---------------------------------------------------------------------------
// rsinv[z][m] = 1 / (fq[z][m] . sk[z])  — analytic pred row-sum (no softmax
// nonlinearity, so sum_n fq.fk[n] == fq.(sum_n fk[n])).
// ---------------------------------------------------------------------------
__global__ __launch_bounds__(256) void rowsum_inv(
    const _Float16* __restrict__ fqH, const float* __restrict__ sk,
    float* __restrict__ rsinv)
{
    const int g = blockIdx.x * 256 + threadIdx.x;   // 0..32767, z uniform/block
    const int z = g >> 10;
    const _Float16* p = fqH + (long)g * 128;
    const float* s = sk + z * 128;
    float acc = 0.f;
#pragma unroll
    for (int d0 = 0; d0 < 128; d0 += 8) {
        half8 v = *(const half8*)(p + d0);
#pragma unroll
        for (int j = 0; j < 8; ++j) acc = fmaf((float)v[j], s[d0 + j], acc);
    }
    rsinv[g] = 1.f / acc;
}

// ---------------------------------------------------------------------------
extern "C" void kernel_launch(void* const* d_in, const int* in_sizes, int n_in,
                              void* d_out, int out_size, void* d_ws, size_t ws_size,
                              hipStream_t stream)
{
    (void)in_sizes; (void)n_in; (void)out_size; (void)ws_size;

    const float* hs  = (const float*)d_in[0];
    const float* Wq  = (const float*)d_in[1];
    const float* bq  = (const float*)d_in[2];
    const float* Wk  = (const float*)d_in[3];
    const float* bk  = (const float*)d_in[4];
    const float* Wv  = (const float*)d_in[5];
    const float* bv  = (const float*)d_in[6];
    const float* Wo  = (const float*)d_in[7];
    const float* bo  = (const float*)d_in[8];
    const float* Wfq = (const float*)d_in[9];
    const float* bfq = (const float*)d_in[10];
    const float* Wfk = (const float*)d_in[11];
    const float* bfk = (const float*)d_in[12];

    float* out0  = (float*)d_out;                       // (B,S,DM)
    float* pred  = out0 + (long)B_ * S_ * DM_;          // (B,H,S,S)
    float* trueA = pred + (long)B_ * NH_ * S_ * S_;     // (B,H,S,S)

    // workspace carve (halves), ~45 MB total
    _Float16* hsH  = (_Float16*)d_ws;                   // 2M
    _Float16* WqH  = hsH + 2 * 1024 * 1024;             // 1M each
    _Float16* WkH  = WqH + 1024 * 1024;
    _Float16* WvH  = WkH + 1024 * 1024;
    _Float16* WoH  = WvH + 1024 * 1024;
    _Float16* WfqH = WoH + 1024 * 1024;                 // 4096 each
    _Float16* WfkH = WfqH + 4096;
    _Float16* QH   = WfkH + 4096;                       // 2M each
    _Float16* KH   = QH + 2 * 1024 * 1024;
    _Float16* VtH  = KH + 2 * 1024 * 1024;              // (B,H,D,S)
    _Float16* ctxH = VtH + 2 * 1024 * 1024;             // (B,S,DM)
    _Float16* fqH  = ctxH + 2 * 1024 * 1024;            // (B,H,S,128)
    _Float16* fkH  = fqH + (long)B_ * NH_ * S_ * 128;

    // sk / rsinv reuse the WqH region (dead after qkv_proj): 16KB + 128KB
    float* sk    = (float*)WqH;
    float* rsinv = sk + 32 * 128;

    const dim3 blk(256);

    // 0) fp32 -> fp16 input conversions
    cvt_f2h<<<2048, blk, 0, stream>>>(hs, hsH, 512 * 1024);
    cvt_f2h<<<1024, blk, 0, stream>>>(Wq, WqH, 256 * 1024);
    cvt_f2h<<<1024, blk, 0, stream>>>(Wk, WkH, 256 * 1024);
    cvt_f2h<<<1024, blk, 0, stream>>>(Wv, WvH, 256 * 1024);
    cvt_f2h<<<1024, blk, 0, stream>>>(Wo, WoH, 256 * 1024);
    cvt_f2h<<<4, blk, 0, stream>>>(Wfq, WfqH, 1024);
    cvt_f2h<<<4, blk, 0, stream>>>(Wfk, WfkH, 1024);

    // 1) fused QKV projection (V transposed per head)
    qkv_proj<<<dim3(8, 16, 3), blk, 0, stream>>>(
        hsH, WqH, WkH, WvH, bq, bk, bv, QH, KH, VtH);

    // 2) fused scores -> softmax -> trueA + ctx (replaces 3 kernels and
    //    ~384 MB of HBM round-trips)
    attn_fused<<<dim3(32, 32), dim3(512), 0, stream>>>(
        QH, KH, VtH, trueA, ctxH);

    // 3) outputs = ctx @ Wo^T + bo (fp32 out); 64x128 tile -> 256 blocks
    mm_nt<64, 128, 32, 64, 0><<<dim3(8, 32, 1), blk, 0, stream>>>(
        ctxH, WoH, bo, nullptr, out0, nullptr, 1024, 1024, 1024, 1024,
        0, 0, 0, 0, 0, 0, 1.f, 0);

    // 4) feature maps -> fqH, fkH (fp16, (B,H,S,128))
    feat_map<<<dim3(16, 32), blk, 0, stream>>>(QH, WfqH, bfq, fqH);
    feat_map<<<dim3(16, 32), blk, 0, stream>>>(KH, WfkH, bfk, fkH);

    // 5) analytic row sums for pred normalization
    sum_fk<<<32, blk, 0, stream>>>(fkH, sk);
    rowsum_inv<<<128, blk, 0, stream>>>(fqH, sk, rsinv);

    // 6) pred = (fq @ fk^T) * rsinv[row]  (normalization fused in epilogue;
    //    replaces separate norm_rows pass over 2x128 MB)
    mm_nt<128, 128, 64, 64, 0><<<dim3(8, 8, 32), blk, 0, stream>>>(
        fqH, fkH, nullptr, rsinv, pred, nullptr, 128, 128, 128, 1024,
        (long)16 * S_ * 128, (long)S_ * 128,
        (long)16 * S_ * 128, (long)S_ * 128,
        16 * SS, SS, 1.f, 0);
}

// Round 2
// 456.477 us; speedup vs baseline: 1.1821x; 1.0655x over previous
//
#include <hip/hip_runtime.h>
#include <math.h>

constexpr int B_ = 2, S_ = 1024, DM_ = 1024, NH_ = 16, HD_ = 64;
constexpr long SD = (long)S_ * DM_;   // per-batch hidden stride (1M)
constexpr long SS = (long)S_ * S_;    // per-head attn stride (1M)

typedef _Float16 half8 __attribute__((ext_vector_type(8)));
typedef _Float16 half4 __attribute__((ext_vector_type(4)));
typedef float floatx4 __attribute__((ext_vector_type(4)));

// async global->LDS, 16 B per lane; LDS dst is wave-uniform base + lane*16
__device__ __forceinline__ void gl_lds16(const void* g, void* l) {
    __builtin_amdgcn_global_load_lds(
        (const __attribute__((address_space(1))) void*)g,
        (__attribute__((address_space(3))) void*)l, 16, 0, 0);
}

// ---------------------------------------------------------------------------
// Segmented fp32 -> fp16 convert for ALL inputs in one launch.
// Segments (float4 units): hs 524288 | Wq/Wk/Wv/Wo 262144 each | Wfq/Wfk 1024.
// Total 1,574,912 float4 -> grid 6152 x 256.
// ---------------------------------------------------------------------------
__global__ __launch_bounds__(256) void cvt_all(
    const float* __restrict__ hs,  const float* __restrict__ Wq,
    const float* __restrict__ Wk,  const float* __restrict__ Wv,
    const float* __restrict__ Wo,  const float* __restrict__ Wfq,
    const float* __restrict__ Wfk,
    _Float16* __restrict__ hsH, _Float16* __restrict__ WqH,
    _Float16* __restrict__ WkH, _Float16* __restrict__ WvH,
    _Float16* __restrict__ WoH, _Float16* __restrict__ WfqH,
    _Float16* __restrict__ WfkH)
{
    long i = (long)blockIdx.x * 256 + threadIdx.x;
    const float* src; _Float16* dst; long off;
    if (i < 524288)       { src = hs;  dst = hsH;  off = i; }
    else if (i < 786432)  { src = Wq;  dst = WqH;  off = i - 524288; }
    else if (i < 1048576) { src = Wk;  dst = WkH;  off = i - 786432; }
    else if (i < 1310720) { src = Wv;  dst = WvH;  off = i - 1048576; }
    else if (i < 1572864) { src = Wo;  dst = WoH;  off = i - 1310720; }
    else if (i < 1573888) { src = Wfq; dst = WfqH; off = i - 1572864; }
    else                  { src = Wfk; dst = WfkH; off = i - 1573888; }
    float4 v = ((const float4*)src)[off];
    half4 h = { (_Float16)v.x, (_Float16)v.y, (_Float16)v.z, (_Float16)v.w };
    ((half4*)dst)[off] = h;
}

// ---------------------------------------------------------------------------
// Unified NT MFMA GEMM: C = scale*(A @ W^T) [+bias] [*rowscale[row]].
// A: (M x K) k-contiguous fp16. W: (N x K) k-contiguous fp16.
// Batched over z=(b*NH+h) via element strides.
// mode 0: fp32 out (Cf).  mode 1: fp16 out (Ch).
// Block 256 = 4 waves in 2x2; wave computes WM x WN via 16x16x32 f16 MFMA.
// BK = 64 staged as two 32-halves (same 64-B-row LDS layout per half ->
// balanced bank coverage; same accumulation order as BK=32; half the
// barriers / vmcnt drains).
// ---------------------------------------------------------------------------
template <int BM, int BN, int WM, int WN>
__global__ __launch_bounds__(256) void mm_nt(
    const _Float16* __restrict__ Ap, const _Float16* __restrict__ Wp,
    const float* __restrict__ bias, const float* __restrict__ rowscale,
    float* __restrict__ Cf,
    _Float16* __restrict__ Ch, int K, int lda, int ldw, int ldc,
    long sAb, long sAh, long sWb, long sWh, long sCb, long sCh,
    float scale, int mode)
{
    constexpr int MI = WM / 16, NI = WN / 16;
    const int z = blockIdx.z, b = z / NH_, h = z % NH_;
    const int wave = threadIdx.x >> 6, lane = threadIdx.x & 63;
    const int m0 = blockIdx.y * BM, n0 = blockIdx.x * BN;
    const int wm = (wave >> 1) * WM, wn = (wave & 1) * WN;
    const int r16 = lane & 15, quad = lane >> 4;

    const _Float16* Az = Ap + (long)b * sAb + (long)h * sAh;
    const _Float16* Wz = Wp + (long)b * sWb + (long)h * sWh;

    __shared__ __align__(16) _Float16 As[2 * BM * 32];
    __shared__ __align__(16) _Float16 Bs[2 * BN * 32];

    floatx4 acc[MI][NI];
#pragma unroll
    for (int i = 0; i < MI; ++i)
#pragma unroll
        for (int j = 0; j < NI; ++j)
#pragma unroll
            for (int r = 0; r < 4; ++r) acc[i][j][r] = 0.f;

    for (int k0 = 0; k0 < K; k0 += 64) {
#pragma unroll
        for (int hf = 0; hf < 2; ++hf) {
#pragma unroll
            for (int c = wave * (BM / 64); c < (wave + 1) * (BM / 64); ++c) {
                const _Float16* g = Az + (long)(m0 + c * 16 + (lane >> 2)) * lda
                                    + k0 + hf * 32 + (lane & 3) * 8;
                gl_lds16(g, &As[hf * BM * 32 + c * 512]);
            }
#pragma unroll
            for (int c = wave * (BN / 64); c < (wave + 1) * (BN / 64); ++c) {
                const _Float16* g = Wz + (long)(n0 + c * 16 + (lane >> 2)) * ldw
                                    + k0 + hf * 32 + (lane & 3) * 8;
                gl_lds16(g, &Bs[hf * BN * 32 + c * 512]);
            }
        }
        __syncthreads();

#pragma unroll
        for (int hf = 0; hf < 2; ++hf) {
            half8 af[MI], bf8[NI];
#pragma unroll
            for (int i = 0; i < MI; ++i)
                af[i] = *(const half8*)&As[hf * BM * 32
                                           + (wm + i * 16 + r16) * 32 + quad * 8];
#pragma unroll
            for (int j = 0; j < NI; ++j)
                bf8[j] = *(const half8*)&Bs[hf * BN * 32
                                            + (wn + j * 16 + r16) * 32 + quad * 8];
#pragma unroll
            for (int i = 0; i < MI; ++i)
#pragma unroll
                for (int j = 0; j < NI; ++j)
                    acc[i][j] = __builtin_amdgcn_mfma_f32_16x16x32_f16(
                        af[i], bf8[j], acc[i][j], 0, 0, 0);
        }
        __syncthreads();
    }

    const long cb = (long)b * sCb + (long)h * sCh;
#pragma unroll
    for (int i = 0; i < MI; ++i) {
#pragma unroll
        for (int j = 0; j < NI; ++j) {
#pragma unroll
            for (int r = 0; r < 4; ++r) {
                int row = m0 + wm + i * 16 + quad * 4 + r;
                int col = n0 + wn + j * 16 + r16;
                float v = acc[i][j][r] * scale;
                if (bias) v += bias[col];
                if (rowscale) v *= rowscale[(long)z * 1024 + row];
                if (mode == 0) Cf[cb + (long)row * ldc + col] = v;
                else           Ch[cb + (long)row * ldc + col] = (_Float16)v;
            }
        }
    }
}

// ---------------------------------------------------------------------------
// Fused QKV projection: z = blockIdx.z selects {Q,K,V}. M=2048, N=1024, K=1024.
// BK=64 two-half staging as in mm_nt. Q,K written fp16 row-major; V written
// fp16 TRANSPOSED per head: VtH[((b*16+h)*64+d)*1024 + s].
// ---------------------------------------------------------------------------
__global__ __launch_bounds__(256) void qkv_proj(
    const _Float16* __restrict__ hsH,
    const _Float16* __restrict__ W0, const _Float16* __restrict__ W1,
    const _Float16* __restrict__ W2,
    const float* __restrict__ b0, const float* __restrict__ b1,
    const float* __restrict__ b2,
    _Float16* __restrict__ QH, _Float16* __restrict__ KH,
    _Float16* __restrict__ VtH)
{
    const int z = blockIdx.z;
    const _Float16* W = (z == 0) ? W0 : (z == 1) ? W1 : W2;
    const float* bias = (z == 0) ? b0 : (z == 1) ? b1 : b2;

    const int wave = threadIdx.x >> 6, lane = threadIdx.x & 63;
    const int m0 = blockIdx.y * 128, n0 = blockIdx.x * 128;
    const int wm = (wave >> 1) * 64, wn = (wave & 1) * 64;
    const int r16 = lane & 15, quad = lane >> 4;

    __shared__ __align__(16) _Float16 As[2 * 128 * 32];
    __shared__ __align__(16) _Float16 Bs[2 * 128 * 32];

    floatx4 acc[4][4];
#pragma unroll
    for (int i = 0; i < 4; ++i)
#pragma unroll
        for (int j = 0; j < 4; ++j)
#pragma unroll
            for (int r = 0; r < 4; ++r) acc[i][j][r] = 0.f;

    for (int k0 = 0; k0 < 1024; k0 += 64) {
#pragma unroll
        for (int hf = 0; hf < 2; ++hf) {
#pragma unroll
            for (int c = wave * 2; c < wave * 2 + 2; ++c) {
                const _Float16* ga = hsH + (long)(m0 + c * 16 + (lane >> 2)) * 1024
                                     + k0 + hf * 32 + (lane & 3) * 8;
                gl_lds16(ga, &As[hf * 4096 + c * 512]);
                const _Float16* gb = W + (long)(n0 + c * 16 + (lane >> 2)) * 1024
                                     + k0 + hf * 32 + (lane & 3) * 8;
                gl_lds16(gb, &Bs[hf * 4096 + c * 512]);
            }
        }
        __syncthreads();

#pragma unroll
        for (int hf = 0; hf < 2; ++hf) {
            half8 af[4], bf8[4];
#pragma unroll
            for (int i = 0; i < 4; ++i)
                af[i] = *(const half8*)&As[hf * 4096
                                           + (wm + i * 16 + r16) * 32 + quad * 8];
#pragma unroll
            for (int j = 0; j < 4; ++j)
                bf8[j] = *(const half8*)&Bs[hf * 4096
                                            + (wn + j * 16 + r16) * 32 + quad * 8];
#pragma unroll
            for (int i = 0; i < 4; ++i)
#pragma unroll
                for (int j = 0; j < 4; ++j)
                    acc[i][j] = __builtin_amdgcn_mfma_f32_16x16x32_f16(
                        af[i], bf8[j], acc[i][j], 0, 0, 0);
        }
        __syncthreads();
    }

    _Float16* dst = (z == 0) ? QH : KH;
#pragma unroll
    for (int i = 0; i < 4; ++i) {
#pragma unroll
        for (int j = 0; j < 4; ++j) {
#pragma unroll
            for (int r = 0; r < 4; ++r) {
                int row = m0 + wm + i * 16 + quad * 4 + r;
                int col = n0 + wn + j * 16 + r16;
                float v = acc[i][j][r] + bias[col];
                if (z < 2) {
                    dst[(long)row * 1024 + col] = (_Float16)v;
                } else {
                    int bb = row >> 10, s = row & 1023;
                    int hh = col >> 6, d = col & 63;
                    VtH[((((long)bb * 16 + hh) * 64 + d) << 10) | s] = (_Float16)v;
                }
            }
        }
    }
}

// ---------------------------------------------------------------------------
// Fused attention block: per (b,h) and 32-row Q block:
//   scores = Q Kh^T (MFMA, fragments straight from global/L2, K=64)
//   softmax in-register (wave shfl_xor + cross-wave LDS reduce)
//   write normalized probs once to trueA (fp32) and keep fp16 P in LDS
//   ctx = P @ V (A from swizzled LDS, B from VtH), write ctxH (B,S,DM) fp16
// Block = 512 thr (8 waves). Scores: wave w owns cols w*128..w*128+128.
// PV: wave -> d-slice (w&3)*16, k-half (w>>2); k-reduce via LDS.
// LDS: single 64 KB buffer, phase-aliased (red arrays / P / k-reduce scratch).
// ---------------------------------------------------------------------------
__global__ __launch_bounds__(512) void attn_fused(
    const _Float16* __restrict__ Q, const _Float16* __restrict__ K,
    const _Float16* __restrict__ Vt, float* __restrict__ trueA,
    _Float16* __restrict__ ctx)
{
    const int z = blockIdx.y, b = z >> 4, h = z & 15;
    const int m0 = blockIdx.x * 32;
    const int wave = threadIdx.x >> 6, lane = threadIdx.x & 63;
    const int r16 = lane & 15, quad = lane >> 4;
    const int c0 = wave * 128;

    __shared__ __align__(16) _Float16 Ps[32 * 1024];   // 64 KB, phase-aliased
    float* redmx = (float*)Ps;          // [8][32]
    float* redsm = (float*)Ps + 256;    // [8][32]
    float* kred  = (float*)Ps;          // [4][2][64][4]

    const _Float16* Qb = Q + (long)b * SD + h * 64;
    const _Float16* Kb = K + (long)b * SD + h * 64;

    // ---- scores: rows m0..m0+31, cols c0..c0+127, K=64
    half8 af[2][2];
#pragma unroll
    for (int mi = 0; mi < 2; ++mi)
#pragma unroll
        for (int ks = 0; ks < 2; ++ks)
            af[mi][ks] = *(const half8*)&Qb[(long)(m0 + mi * 16 + r16) * DM_
                                            + ks * 32 + quad * 8];

    floatx4 acc[2][8];
#pragma unroll
    for (int mi = 0; mi < 2; ++mi)
#pragma unroll
        for (int nj = 0; nj < 8; ++nj)
#pragma unroll
            for (int r = 0; r < 4; ++r) acc[mi][nj][r] = 0.f;

#pragma unroll
    for (int ks = 0; ks < 2; ++ks) {
#pragma unroll
        for (int nj = 0; nj < 8; ++nj) {
            half8 bf = *(const half8*)&Kb[(long)(c0 + nj * 16 + r16) * DM_
                                          + ks * 32 + quad * 8];
            acc[0][nj] = __builtin_amdgcn_mfma_f32_16x16x32_f16(
                af[0][ks], bf, acc[0][nj], 0, 0, 0);
            acc[1][nj] = __builtin_amdgcn_mfma_f32_16x16x32_f16(
                af[1][ks], bf, acc[1][nj], 0, 0, 0);
        }
    }

    // ---- row max over all 1024 cols
    float rmx[2][4];
#pragma unroll
    for (int mi = 0; mi < 2; ++mi)
#pragma unroll
        for (int r = 0; r < 4; ++r) {
            float m = acc[mi][0][r];
#pragma unroll
            for (int nj = 1; nj < 8; ++nj) m = fmaxf(m, acc[mi][nj][r]);
#pragma unroll
            for (int o = 1; o <= 8; o <<= 1) m = fmaxf(m, __shfl_xor(m, o, 64));
            rmx[mi][r] = m;
        }
    if (r16 == 0) {
#pragma unroll
        for (int mi = 0; mi < 2; ++mi)
#pragma unroll
            for (int r = 0; r < 4; ++r)
                redmx[wave * 32 + mi * 16 + quad * 4 + r] = rmx[mi][r];
    }
    __syncthreads();
    float mx[2][4];
#pragma unroll
    for (int mi = 0; mi < 2; ++mi)
#pragma unroll
        for (int r = 0; r < 4; ++r) {
            float m = redmx[mi * 16 + quad * 4 + r];
#pragma unroll
            for (int w = 1; w < 8; ++w)
                m = fmaxf(m, redmx[w * 32 + mi * 16 + quad * 4 + r]);
            mx[mi][r] = m;
        }

    // ---- p = exp((s - max) * 1/8), row sum
    float rsm[2][4];
#pragma unroll
    for (int mi = 0; mi < 2; ++mi)
#pragma unroll
        for (int r = 0; r < 4; ++r) {
            float s = 0.f;
#pragma unroll
            for (int nj = 0; nj < 8; ++nj) {
                float p = __expf((acc[mi][nj][r] - mx[mi][r]) * 0.125f);
                acc[mi][nj][r] = p;
                s += p;
            }
#pragma unroll
            for (int o = 1; o <= 8; o <<= 1) s += __shfl_xor(s, o, 64);
            rsm[mi][r] = s;
        }
    if (r16 == 0) {
#pragma unroll
        for (int mi = 0; mi < 2; ++mi)
#pragma unroll
            for (int r = 0; r < 4; ++r)
                redsm[wave * 32 + mi * 16 + quad * 4 + r] = rsm[mi][r];
    }
    __syncthreads();
    float inv[2][4];
#pragma unroll
    for (int mi = 0; mi < 2; ++mi)
#pragma unroll
        for (int r = 0; r < 4; ++r) {
            float s = 0.f;
#pragma unroll
            for (int w = 0; w < 8; ++w)
                s += redsm[w * 32 + mi * 16 + quad * 4 + r];
            inv[mi][r] = 1.f / s;
        }
    __syncthreads();   // red reads done; Ps region can be overwritten

    // ---- write normalized probs: trueA (fp32) + Ps (fp16, XOR-swizzled: G4)
    float* Ta = trueA + (long)z * SS + (long)m0 * S_;
#pragma unroll
    for (int mi = 0; mi < 2; ++mi) {
#pragma unroll
        for (int r = 0; r < 4; ++r) {
            const int row = mi * 16 + quad * 4 + r;
            const int sw = (row & 7) << 3;
            const float iv = inv[mi][r];
#pragma unroll
            for (int nj = 0; nj < 8; ++nj) {
                const int col = c0 + nj * 16 + r16;
                const float v = acc[mi][nj][r] * iv;
                Ta[(long)row * S_ + col] = v;
                Ps[row * 1024 + (col ^ sw)] = (_Float16)v;
            }
        }
    }
    __syncthreads();   // Ps complete

    // ---- ctx = P @ V
    const int d0 = (wave & 3) * 16, kr = wave >> 2;
    const _Float16* Vb = Vt + ((long)z * 64 + d0 + r16) * (long)S_;
    floatx4 c2[2];
#pragma unroll
    for (int mi = 0; mi < 2; ++mi)
#pragma unroll
        for (int r = 0; r < 4; ++r) c2[mi][r] = 0.f;

    const int swz = (r16 & 7) << 3;     // same for rows r16 and 16+r16
#pragma unroll 4
    for (int k0 = kr * 512; k0 < kr * 512 + 512; k0 += 32) {
        half8 pa0 = *(const half8*)&Ps[r16 * 1024 + ((k0 + quad * 8) ^ swz)];
        half8 pa1 = *(const half8*)&Ps[(16 + r16) * 1024 + ((k0 + quad * 8) ^ swz)];
        half8 vf  = *(const half8*)&Vb[k0 + quad * 8];
        c2[0] = __builtin_amdgcn_mfma_f32_16x16x32_f16(pa0, vf, c2[0], 0, 0, 0);
        c2[1] = __builtin_amdgcn_mfma_f32_16x16x32_f16(pa1, vf, c2[1], 0, 0, 0);
    }

    __syncthreads();   // all Ps reads done; reuse LDS for k-reduce
    if (kr == 1) {
#pragma unroll
        for (int mi = 0; mi < 2; ++mi)
            *(floatx4*)&kred[(((wave & 3) * 2 + mi) * 64 + lane) * 4] = c2[mi];
    }
    __syncthreads();
    if (kr == 0) {
        _Float16* Cb = ctx + (long)b * SD + h * 64;
#pragma unroll
        for (int mi = 0; mi < 2; ++mi) {
            c2[mi] += *(const floatx4*)&kred[((wave * 2 + mi) * 64 + lane) * 4];
#pragma unroll
            for (int r = 0; r < 4; ++r) {
                const int srow = m0 + mi * 16 + quad * 4 + r;
                Cb[(long)srow * DM_ + d0 + r16] = (_Float16)c2[mi][r];
            }
        }
    }
}

// ---------------------------------------------------------------------------
// Hedgehog feature map, both tensors in one launch (blockIdx.z: 0=fq, 1=fk).
// Per (b,h): Y = Xh @ Wf^T + bf (K=64), out = fp16 [exp(Y)|exp(-Y)] into
// (B,H,S,128). For fk, per-block column partial sums are written to
// skp[(z*16+mb)*128 + c] (deterministic, no atomics) for the analytic pred
// row-sum.
// ---------------------------------------------------------------------------
__global__ __launch_bounds__(256) void feat_map2(
    const _Float16* __restrict__ QH, const _Float16* __restrict__ KH,
    const _Float16* __restrict__ Wfq, const _Float16* __restrict__ Wfk,
    const float* __restrict__ bfq, const float* __restrict__ bfk,
    _Float16* __restrict__ fqH, _Float16* __restrict__ fkH,
    float* __restrict__ skp)
{
    const int which = blockIdx.z;
    const _Float16* Xh = which ? KH : QH;
    const _Float16* Wf = which ? Wfk : Wfq;
    const float* bf    = which ? bfk : bfq;
    _Float16* outH     = which ? fkH : fqH;

    const int z = blockIdx.y, b = z >> 4, h = z & 15;
    const int mb = blockIdx.x, m0 = mb * 64;
    __shared__ float Xs[64][65];
    __shared__ float Ws[64][65];
    __shared__ float red[16][128];
    const _Float16* Xb = Xh + (long)b * SD + h * 64;
    for (int i = threadIdx.x; i < 4096; i += 256) {
        int r = i >> 6, c = i & 63;
        Xs[r][c] = (float)Xb[(long)(m0 + r) * 1024 + c];
        Ws[r][c] = (float)Wf[i];
    }
    __syncthreads();
    const int tmg = threadIdx.x >> 4;
    const int tm = tmg * 4, tn = (threadIdx.x & 15) * 4;
    float acc[4][4] = {{0.f}};
    for (int k = 0; k < 64; ++k) {
        float xv[4], wv[4];
#pragma unroll
        for (int i = 0; i < 4; ++i) xv[i] = Xs[tm + i][k];
#pragma unroll
        for (int j = 0; j < 4; ++j) wv[j] = Ws[tn + j][k];
#pragma unroll
        for (int i = 0; i < 4; ++i)
#pragma unroll
            for (int j = 0; j < 4; ++j) acc[i][j] = fmaf(xv[i], wv[j], acc[i][j]);
    }
    float sp[4] = {0.f, 0.f, 0.f, 0.f}, sn[4] = {0.f, 0.f, 0.f, 0.f};
#pragma unroll
    for (int i = 0; i < 4; ++i) {
        long base = ((long)z * S_ + m0 + tm + i) * 128;
#pragma unroll
        for (int j = 0; j < 4; ++j) {
            float y = acc[i][j] + bf[tn + j];
            float ep = expf(y), en = expf(-y);
            outH[base + tn + j]      = (_Float16)ep;
            outH[base + 64 + tn + j] = (_Float16)en;
            sp[j] += ep; sn[j] += en;
        }
    }
    if (which) {
#pragma unroll
        for (int j = 0; j < 4; ++j) {
            red[tmg][tn + j]      = sp[j];
            red[tmg][64 + tn + j] = sn[j];
        }
        __syncthreads();
        if (threadIdx.x < 128) {
            float s = 0.f;
#pragma unroll
            for (int g = 0; g < 16; ++g) s += red[g][threadIdx.x];
            skp[((long)z * 16 + mb) * 128 + threadIdx.x] = s;
        }
    }
}

// ---------------------------------------------------------------------------
// rsinv[z][m] = 1 / (fq[z][m] . sk[z]) where sk[z] = sum over 16 m-block
// partials skp. Analytic pred row-sum (no softmax nonlinearity, so
// sum_n fq.fk[n] == fq.(sum_n fk[n])). One block = 256 rows of one z.
// ---------------------------------------------------------------------------
__global__ __launch_bounds__(256) void rowsum_inv(
    const _Float16* __restrict__ fqH, const float* __restrict__ skp,
    float* __restrict__ rsinv)
{
    const int g = blockIdx.x * 256 + threadIdx.x;   // 0..32767, z uniform/block
    const int z = g >> 10;
    __shared__ float skz[128];
    if (threadIdx.x < 128) {
        float s = 0.f;
#pragma unroll
        for (int m = 0; m < 16; ++m)
            s += skp[((long)z * 16 + m) * 128 + threadIdx.x];
        skz[threadIdx.x] = s;
    }
    __syncthreads();
    const _Float16* p = fqH + (long)g * 128;
    float acc = 0.f;
#pragma unroll
    for (int d0 = 0; d0 < 128; d0 += 8) {
        half8 v = *(const half8*)(p + d0);
#pragma unroll
        for (int j = 0; j < 8; ++j) acc = fmaf((float)v[j], skz[d0 + j], acc);
    }
    rsinv[g] = 1.f / acc;
}

// ---------------------------------------------------------------------------
extern "C" void kernel_launch(void* const* d_in, const int* in_sizes, int n_in,
                              void* d_out, int out_size, void* d_ws, size_t ws_size,
                              hipStream_t stream)
{
    (void)in_sizes; (void)n_in; (void)out_size; (void)ws_size;

    const float* hs  = (const float*)d_in[0];
    const float* Wq  = (const float*)d_in[1];
    const float* bq  = (const float*)d_in[2];
    const float* Wk  = (const float*)d_in[3];
    const float* bk  = (const float*)d_in[4];
    const float* Wv  = (const float*)d_in[5];
    const float* bv  = (const float*)d_in[6];
    const float* Wo  = (const float*)d_in[7];
    const float* bo  = (const float*)d_in[8];
    const float* Wfq = (const float*)d_in[9];
    const float* bfq = (const float*)d_in[10];
    const float* Wfk = (const float*)d_in[11];
    const float* bfk = (const float*)d_in[12];

    float* out0  = (float*)d_out;                       // (B,S,DM)
    float* pred  = out0 + (long)B_ * S_ * DM_;          // (B,H,S,S)
    float* trueA = pred + (long)B_ * NH_ * S_ * S_;     // (B,H,S,S)

    // workspace carve (halves), ~45 MB total
    _Float16* hsH  = (_Float16*)d_ws;                   // 2M
    _Float16* WqH  = hsH + 2 * 1024 * 1024;             // 1M each
    _Float16* WkH  = WqH + 1024 * 1024;
    _Float16* WvH  = WkH + 1024 * 1024;
    _Float16* WoH  = WvH + 1024 * 1024;
    _Float16* WfqH = WoH + 1024 * 1024;                 // 4096 each
    _Float16* WfkH = WfqH + 4096;
    _Float16* QH   = WfkH + 4096;                       // 2M each
    _Float16* KH   = QH + 2 * 1024 * 1024;
    _Float16* VtH  = KH + 2 * 1024 * 1024;              // (B,H,D,S)
    _Float16* ctxH = VtH + 2 * 1024 * 1024;             // (B,S,DM)
    _Float16* fqH  = ctxH + 2 * 1024 * 1024;            // (B,H,S,128)
    _Float16* fkH  = fqH + (long)B_ * NH_ * S_ * 128;

    // skp (256 KB) reuses WqH region (dead after qkv_proj, written by
    // feat_map2 in step 4); rsinv (128 KB) reuses WkH region (dead after
    // qkv_proj, written by rowsum_inv in step 5). No zeroing needed: both
    // are fully overwritten with plain stores before being read.
    float* skp   = (float*)WqH;
    float* rsinv = (float*)WkH;

    const dim3 blk(256);

    // 0) all fp32 -> fp16 input conversions, one launch
    cvt_all<<<6152, blk, 0, stream>>>(
        hs, Wq, Wk, Wv, Wo, Wfq, Wfk,
        hsH, WqH, WkH, WvH, WoH, WfqH, WfkH);

    // 1) fused QKV projection (V transposed per head)
    qkv_proj<<<dim3(8, 16, 3), blk, 0, stream>>>(
        hsH, WqH, WkH, WvH, bq, bk, bv, QH, KH, VtH);

    // 2) fused scores -> softmax -> trueA + ctx
    attn_fused<<<dim3(32, 32), dim3(512), 0, stream>>>(
        QH, KH, VtH, trueA, ctxH);

    // 3) outputs = ctx @ Wo^T + bo (fp32 out)
    mm_nt<64, 128, 32, 64><<<dim3(8, 32, 1), blk, 0, stream>>>(
        ctxH, WoH, bo, nullptr, out0, nullptr, 1024, 1024, 1024, 1024,
        0, 0, 0, 0, 0, 0, 1.f, 0);

    // 4) feature maps -> fqH, fkH + per-block fk column partials (skp)
    feat_map2<<<dim3(16, 32, 2), blk, 0, stream>>>(
        QH, KH, WfqH, WfkH, bfq, bfk, fqH, fkH, skp);

    // 5) analytic row-sum inverse for pred normalization
    rowsum_inv<<<128, blk, 0, stream>>>(fqH, skp, rsinv);

    // 6) pred = (fq @ fk^T) * rsinv[row]  (normalization fused in epilogue)
    mm_nt<128, 128, 64, 64><<<dim3(8, 8, 32), blk, 0, stream>>>(
        fqH, fkH, nullptr, rsinv, pred, nullptr, 128, 128, 128, 1024,
        (long)16 * S_ * 128, (long)S_ * 128,
        (long)16 * S_ * 128, (long)S_ * 128,
        16 * SS, SS, 1.f, 0);
}